// Round 1
// baseline (1279.207 us; speedup 1.0000x reference)
//
#include <hip/hip_runtime.h>

// ---------------- types / helpers ----------------
typedef __attribute__((ext_vector_type(8))) short bf16x8;
typedef __attribute__((ext_vector_type(4))) short short4v;
typedef __attribute__((ext_vector_type(4))) float f32x4;

__device__ __forceinline__ float bf2f(short s) {
    union { unsigned u; float f; } c;
    c.u = ((unsigned)(unsigned short)s) << 16;
    return c.f;
}
__device__ __forceinline__ short f2bf(float f) {
    union { float f; unsigned u; } c; c.f = f;
    unsigned r = (c.u + 0x7fffu + ((c.u >> 16) & 1u)) >> 16;
    return (short)r;
}

#define AS1(p) ((__attribute__((address_space(1))) void*)(void*)(p))
#define AS3(p) ((__attribute__((address_space(3))) void*)(p))

// ---------------- generic bf16 GEMM: C = A[MxK] * B^T[NxK] ----------------
// MODE 0: C bf16 = acc*scale
// MODE 1: C bf16 = gelu(acc + bias[col])
// MODE 2: C f32  = acc + bias[col] + resid[row,col]
template<int MODE>
__global__ __launch_bounds__(256) void gemm_bt(
    const short* __restrict__ A, int lda, long sAb, long sAh,
    const short* __restrict__ B, int ldb, long sBb, long sBh,
    void* __restrict__ Cv, int ldc, long sCb, long sCh,
    const float* __restrict__ bias, const float* __restrict__ resid,
    int M, int N, int K, int ntn, int H, float scale)
{
    __shared__ short As[128 * 32];
    __shared__ short Bs[128 * 32];

    const int z  = blockIdx.y;
    const int bb = z / H, hh = z % H;
    const short* Ab = A + sAb * bb + sAh * hh;
    const short* Bb = B + sBb * bb + sBh * hh;
    const long cb = sCb * bb + sCh * hh;

    const int tm = (blockIdx.x / ntn) * 128;
    const int tn = (blockIdx.x % ntn) * 128;

    const int tid = threadIdx.x;
    const int w = tid >> 6, l = tid & 63;
    const int lr = l >> 2, lc = l & 3;          // staging: row-in-chunk, 16B chunk
    const int lane16 = l & 15, kg = l >> 4;     // fragment indices
    const int wr = (w >> 1) * 64, wc = (w & 1) * 64;

    f32x4 acc[4][4] = {};

    for (int k0 = 0; k0 < K; k0 += 32) {
        // ---- stage A,B tiles (128x32 bf16 each) via global_load_lds width 16 ----
        #pragma unroll
        for (int i = 0; i < 2; ++i) {
            int row = (i * 4 + w) * 16 + lr;
            int ga = tm + row; if (ga > M - 1) ga = M - 1;
            const short* srca = Ab + (long)ga * lda + k0 + lc * 8;
            __builtin_amdgcn_global_load_lds(AS1(srca), AS3(As + (i * 4 + w) * 16 * 32), 16, 0, 0);
            int gb = tn + row; if (gb > N - 1) gb = N - 1;
            const short* srcb = Bb + (long)gb * ldb + k0 + lc * 8;
            __builtin_amdgcn_global_load_lds(AS1(srcb), AS3(Bs + (i * 4 + w) * 16 * 32), 16, 0, 0);
        }
        __syncthreads();

        bf16x8 af[4], bfr[4];
        #pragma unroll
        for (int m = 0; m < 4; ++m)
            af[m] = *(const bf16x8*)(As + (wr + m * 16 + lane16) * 32 + kg * 8);
        #pragma unroll
        for (int n = 0; n < 4; ++n)
            bfr[n] = *(const bf16x8*)(Bs + (wc + n * 16 + lane16) * 32 + kg * 8);
        #pragma unroll
        for (int m = 0; m < 4; ++m)
            #pragma unroll
            for (int n = 0; n < 4; ++n)
                acc[m][n] = __builtin_amdgcn_mfma_f32_16x16x32_bf16(af[m], bfr[n], acc[m][n], 0, 0, 0);
        __syncthreads();
    }

    // ---- epilogue ----
    if (MODE == 2) {
        float* C = (float*)Cv;
        #pragma unroll
        for (int m = 0; m < 4; ++m)
            #pragma unroll
            for (int n = 0; n < 4; ++n) {
                int col = tn + wc + n * 16 + lane16;
                if (col >= N) continue;
                #pragma unroll
                for (int r = 0; r < 4; ++r) {
                    int row = tm + wr + m * 16 + kg * 4 + r;
                    if (row >= M) continue;
                    long idx = cb + (long)row * ldc + col;
                    C[idx] = acc[m][n][r] * scale + bias[col] + resid[idx];
                }
            }
    } else {
        short* C = (short*)Cv;
        #pragma unroll
        for (int m = 0; m < 4; ++m)
            #pragma unroll
            for (int n = 0; n < 4; ++n) {
                int col = tn + wc + n * 16 + lane16;
                if (col >= N) continue;
                #pragma unroll
                for (int r = 0; r < 4; ++r) {
                    int row = tm + wr + m * 16 + kg * 4 + r;
                    if (row >= M) continue;
                    float v = acc[m][n][r] * scale;
                    if (MODE == 1) {
                        v += bias[col];
                        v = 0.5f * v * (1.0f + erff(v * 0.7071067811865476f));
                    }
                    C[cb + (long)row * ldc + col] = f2bf(v);
                }
            }
    }
}

// ---------------- LayerNorm fp32 -> bf16 (one block per row of 1024) ----------------
__global__ __launch_bounds__(256) void ln_bf16(const float* __restrict__ x,
                                               const float* __restrict__ g,
                                               const float* __restrict__ b,
                                               short* __restrict__ h)
{
    const long row = blockIdx.x;
    const int tid = threadIdx.x;
    float4 v = ((const float4*)(x + row * 1024))[tid];
    float s  = v.x + v.y + v.z + v.w;
    float s2 = v.x * v.x + v.y * v.y + v.z * v.z + v.w * v.w;
    #pragma unroll
    for (int off = 1; off < 64; off <<= 1) {
        s  += __shfl_xor(s, off);
        s2 += __shfl_xor(s2, off);
    }
    __shared__ float rs[4], rs2[4];
    int w = tid >> 6;
    if ((tid & 63) == 0) { rs[w] = s; rs2[w] = s2; }
    __syncthreads();
    s  = rs[0] + rs[1] + rs[2] + rs[3];
    s2 = rs2[0] + rs2[1] + rs2[2] + rs2[3];
    float mu  = s * (1.0f / 1024.0f);
    float var = s2 * (1.0f / 1024.0f) - mu * mu;
    float inv = rsqrtf(var + 1e-5f);
    float4 gv = ((const float4*)g)[tid];
    float4 bv = ((const float4*)b)[tid];
    short4v o;
    o[0] = f2bf((v.x - mu) * inv * gv.x + bv.x);
    o[1] = f2bf((v.y - mu) * inv * gv.y + bv.y);
    o[2] = f2bf((v.z - mu) * inv * gv.z + bv.z);
    o[3] = f2bf((v.w - mu) * inv * gv.w + bv.w);
    ((short4v*)(h + row * 1024))[tid] = o;
}

// ---------------- row softmax in place on bf16 rows of 1024 ----------------
__global__ __launch_bounds__(256) void softmax_rows(short* __restrict__ sp)
{
    const long row = blockIdx.x;
    short* p = sp + row * 1024;
    const int tid = threadIdx.x;
    short4v v = ((short4v*)p)[tid];
    float f0 = bf2f(v[0]), f1 = bf2f(v[1]), f2 = bf2f(v[2]), f3 = bf2f(v[3]);
    float m = fmaxf(fmaxf(f0, f1), fmaxf(f2, f3));
    #pragma unroll
    for (int off = 1; off < 64; off <<= 1) m = fmaxf(m, __shfl_xor(m, off));
    __shared__ float red[8];
    int w = tid >> 6;
    if ((tid & 63) == 0) red[w] = m;
    __syncthreads();
    m = fmaxf(fmaxf(red[0], red[1]), fmaxf(red[2], red[3]));
    float e0 = expf(f0 - m), e1 = expf(f1 - m), e2 = expf(f2 - m), e3 = expf(f3 - m);
    float s = e0 + e1 + e2 + e3;
    #pragma unroll
    for (int off = 1; off < 64; off <<= 1) s += __shfl_xor(s, off);
    if ((tid & 63) == 0) red[4 + w] = s;
    __syncthreads();
    s = red[4] + red[5] + red[6] + red[7];
    float inv = 1.0f / s;
    v[0] = f2bf(e0 * inv); v[1] = f2bf(e1 * inv); v[2] = f2bf(e2 * inv); v[3] = f2bf(e3 * inv);
    ((short4v*)p)[tid] = v;
}

// ---------------- transpose fp32 [R][C] -> bf16 [C][R] ----------------
__global__ __launch_bounds__(256) void wconv_t(const float* __restrict__ in,
                                               short* __restrict__ out, int R, int C)
{
    __shared__ float t[32][33];
    const int c0 = blockIdx.x * 32, r0 = blockIdx.y * 32;
    const int tx = threadIdx.x & 31, ty = threadIdx.x >> 5;
    #pragma unroll
    for (int i = 0; i < 4; ++i)
        t[ty + i * 8][tx] = in[(long)(r0 + ty + i * 8) * C + c0 + tx];
    __syncthreads();
    #pragma unroll
    for (int i = 0; i < 4; ++i)
        out[(long)(c0 + ty + i * 8) * R + r0 + tx] = f2bf(t[tx][ty + i * 8]);
}

// ---------------- per-head V transpose: bf16 [m][d] -> vt[z][d][m] ----------------
__global__ __launch_bounds__(256) void vtrans(const short* __restrict__ src, int ld, int col_off,
                                              short* __restrict__ vt)
{
    __shared__ short t[32][33];
    const int z = blockIdx.z, bb = z >> 4, hh = z & 15;
    const int m0 = blockIdx.x * 32, d0 = blockIdx.y * 32;
    const int tx = threadIdx.x & 31, ty = threadIdx.x >> 5;
    const short* sp = src + (long)(bb * 1024) * ld + col_off + hh * 64;
    #pragma unroll
    for (int i = 0; i < 4; ++i)
        t[ty + i * 8][tx] = sp[(long)(m0 + ty + i * 8) * ld + d0 + tx];
    __syncthreads();
    short* op = vt + (long)z * 64 * 1024;
    #pragma unroll
    for (int i = 0; i < 4; ++i)
        op[(long)(d0 + ty + i * 8) * 1024 + m0 + tx] = t[tx][ty + i * 8];
}

// ---------------- elementwise fp32 -> bf16 ----------------
__global__ __launch_bounds__(256) void f2bf_vec(const float* __restrict__ in,
                                                short* __restrict__ out, int n4)
{
    int i = blockIdx.x * 256 + threadIdx.x;
    if (i < n4) {
        float4 v = ((const float4*)in)[i];
        short4v o;
        o[0] = f2bf(v.x); o[1] = f2bf(v.y); o[2] = f2bf(v.z); o[3] = f2bf(v.w);
        ((short4v*)out)[i] = o;
    }
}

// ---------------- host side ----------------
template<int MODE>
static void launch_gemm(const short* A, int lda, long sAb, long sAh,
                        const short* B, int ldb, long sBb, long sBh,
                        void* C, int ldc, long sCb, long sCh,
                        const float* bias, const float* resid,
                        int M, int N, int K, int batch, int H, float scale, hipStream_t stream)
{
    int ntm = (M + 127) / 128, ntn = (N + 127) / 128;
    dim3 grid(ntm * ntn, batch);
    gemm_bt<MODE><<<grid, 256, 0, stream>>>(A, lda, sAb, sAh, B, ldb, sBb, sBh,
                                            C, ldc, sCb, sCh, bias, resid,
                                            M, N, K, ntn, H, scale);
}

extern "C" void kernel_launch(void* const* d_in, const int* in_sizes, int n_in,
                              void* d_out, int out_size, void* d_ws, size_t ws_size,
                              hipStream_t stream)
{
    const float* x_in  = (const float*)d_in[0];
    const float* ctx   = (const float*)d_in[1];
    const float* ln1_g = (const float*)d_in[2];
    const float* ln1_b = (const float*)d_in[3];
    const float* w_qkv = (const float*)d_in[4];
    const float* w_o1  = (const float*)d_in[5];
    const float* b_o1  = (const float*)d_in[6];
    const float* ln2_g = (const float*)d_in[7];
    const float* ln2_b = (const float*)d_in[8];
    const float* w_q   = (const float*)d_in[9];
    const float* w_k   = (const float*)d_in[10];
    const float* w_v   = (const float*)d_in[11];
    const float* w_o2  = (const float*)d_in[12];
    const float* b_o2  = (const float*)d_in[13];
    const float* ln3_g = (const float*)d_in[14];
    const float* ln3_b = (const float*)d_in[15];
    const float* w_ff1 = (const float*)d_in[16];
    const float* b_ff1 = (const float*)d_in[17];
    const float* w_ff2 = (const float*)d_in[18];
    const float* b_ff2 = (const float*)d_in[19];
    float* xo = (float*)d_out;

    char* p = (char*)d_ws;
    short* wbuf   = (short*)(p);              // 8,388,608 B  (max 4096x1024 bf16)
    short* hbuf   = (short*)(p + 8388608);    // 4 MB
    short* qkvbuf = (short*)(p + 12582912);   // 12.58 MB
    short* scores = (short*)(p + 25165824);   // 64 MB
    short* vt     = (short*)(p + 92274688);   // 4 MB
    short* aout   = (short*)(p + 96468992);   // 4 MB
    short* ffbuf  = (short*)(p + 100663296);  // 16 MB
    short* ctxbuf = (short*)(p + 117440512);  // 4 MB  (total ~121.6 MB)

    // residual stream lives in d_out (fp32)
    hipMemcpyAsync(xo, x_in, (size_t)2 * 1024 * 1024 * 4, hipMemcpyDeviceToDevice, stream);
    f2bf_vec<<<2048, 256, 0, stream>>>(ctx, ctxbuf, 2 * 1024 * 1024 / 4);

    for (int l = 0; l < 2; ++l) {
        // ======== self attention ========
        ln_bf16<<<2048, 256, 0, stream>>>(xo, ln1_g + l * 1024, ln1_b + l * 1024, hbuf);
        wconv_t<<<dim3(3072 / 32, 1024 / 32), 256, 0, stream>>>(w_qkv + (long)l * 1024 * 3072, wbuf, 1024, 3072);
        launch_gemm<0>(hbuf, 1024, 0, 0, wbuf, 1024, 0, 0, qkvbuf, 3072, 0, 0,
                       nullptr, nullptr, 2048, 3072, 1024, 1, 1, 1.0f, stream);
        // scores = scale * Q K^T   (batched over 32 (b,h))
        launch_gemm<0>(qkvbuf, 3072, 1024L * 3072, 64,
                       qkvbuf + 1024, 3072, 1024L * 3072, 64,
                       scores, 1024, 16L * 1024 * 1024, 1024L * 1024,
                       nullptr, nullptr, 1024, 1024, 64, 32, 16, 0.125f, stream);
        softmax_rows<<<32768, 256, 0, stream>>>(scores);
        vtrans<<<dim3(32, 2, 32), 256, 0, stream>>>(qkvbuf, 3072, 2048, vt);
        launch_gemm<0>(scores, 1024, 16L * 1024 * 1024, 1024L * 1024,
                       vt, 1024, 16L * 64 * 1024, 64L * 1024,
                       aout, 1024, 1024L * 1024, 64,
                       nullptr, nullptr, 1024, 64, 1024, 32, 16, 1.0f, stream);
        wconv_t<<<dim3(32, 32), 256, 0, stream>>>(w_o1 + (long)l * 1024 * 1024, wbuf, 1024, 1024);
        launch_gemm<2>(aout, 1024, 0, 0, wbuf, 1024, 0, 0, xo, 1024, 0, 0,
                       b_o1 + l * 1024, xo, 2048, 1024, 1024, 1, 1, 1.0f, stream);

        // ======== cross attention ========
        ln_bf16<<<2048, 256, 0, stream>>>(xo, ln2_g + l * 1024, ln2_b + l * 1024, hbuf);
        short* q2 = qkvbuf;
        short* k2 = qkvbuf + 2048 * 1024;
        short* v2 = qkvbuf + 2 * 2048 * 1024;
        wconv_t<<<dim3(32, 32), 256, 0, stream>>>(w_q + (long)l * 1048576, wbuf, 1024, 1024);
        launch_gemm<0>(hbuf, 1024, 0, 0, wbuf, 1024, 0, 0, q2, 1024, 0, 0,
                       nullptr, nullptr, 2048, 1024, 1024, 1, 1, 1.0f, stream);
        wconv_t<<<dim3(32, 32), 256, 0, stream>>>(w_k + (long)l * 1048576, wbuf, 1024, 1024);
        launch_gemm<0>(ctxbuf, 1024, 0, 0, wbuf, 1024, 0, 0, k2, 1024, 0, 0,
                       nullptr, nullptr, 2048, 1024, 1024, 1, 1, 1.0f, stream);
        wconv_t<<<dim3(32, 32), 256, 0, stream>>>(w_v + (long)l * 1048576, wbuf, 1024, 1024);
        launch_gemm<0>(ctxbuf, 1024, 0, 0, wbuf, 1024, 0, 0, v2, 1024, 0, 0,
                       nullptr, nullptr, 2048, 1024, 1024, 1, 1, 1.0f, stream);
        launch_gemm<0>(q2, 1024, 1024L * 1024, 64,
                       k2, 1024, 1024L * 1024, 64,
                       scores, 1024, 16L * 1024 * 1024, 1024L * 1024,
                       nullptr, nullptr, 1024, 1024, 64, 32, 16, 0.125f, stream);
        softmax_rows<<<32768, 256, 0, stream>>>(scores);
        vtrans<<<dim3(32, 2, 32), 256, 0, stream>>>(v2, 1024, 0, vt);
        launch_gemm<0>(scores, 1024, 16L * 1024 * 1024, 1024L * 1024,
                       vt, 1024, 16L * 64 * 1024, 64L * 1024,
                       aout, 1024, 1024L * 1024, 64,
                       nullptr, nullptr, 1024, 64, 1024, 32, 16, 1.0f, stream);
        wconv_t<<<dim3(32, 32), 256, 0, stream>>>(w_o2 + (long)l * 1048576, wbuf, 1024, 1024);
        launch_gemm<2>(aout, 1024, 0, 0, wbuf, 1024, 0, 0, xo, 1024, 0, 0,
                       b_o2 + l * 1024, xo, 2048, 1024, 1024, 1, 1, 1.0f, stream);

        // ======== FFN ========
        ln_bf16<<<2048, 256, 0, stream>>>(xo, ln3_g + l * 1024, ln3_b + l * 1024, hbuf);
        wconv_t<<<dim3(4096 / 32, 1024 / 32), 256, 0, stream>>>(w_ff1 + (long)l * 1024 * 4096, wbuf, 1024, 4096);
        launch_gemm<1>(hbuf, 1024, 0, 0, wbuf, 1024, 0, 0, ffbuf, 4096, 0, 0,
                       b_ff1 + l * 4096, nullptr, 2048, 4096, 1024, 1, 1, 1.0f, stream);
        wconv_t<<<dim3(1024 / 32, 4096 / 32), 256, 0, stream>>>(w_ff2 + (long)l * 4096 * 1024, wbuf, 4096, 1024);
        launch_gemm<2>(ffbuf, 4096, 0, 0, wbuf, 4096, 0, 0, xo, 1024, 0, 0,
                       b_ff2 + l * 1024, xo, 2048, 1024, 4096, 1, 1, 1.0f, stream);
    }
}

// Round 2
// 910.546 us; speedup vs baseline: 1.4049x; 1.4049x over previous
//
#include <hip/hip_runtime.h>

// ---------------- types / helpers ----------------
typedef __attribute__((ext_vector_type(8))) short bf16x8;
typedef __attribute__((ext_vector_type(4))) short short4v;
typedef __attribute__((ext_vector_type(4))) float f32x4;

__device__ __forceinline__ float bf2f(short s) {
    union { unsigned u; float f; } c;
    c.u = ((unsigned)(unsigned short)s) << 16;
    return c.f;
}
__device__ __forceinline__ short f2bf(float f) {
    union { float f; unsigned u; } c; c.f = f;
    unsigned r = (c.u + 0x7fffu + ((c.u >> 16) & 1u)) >> 16;
    return (short)r;
}

#define AS1(p) ((__attribute__((address_space(1))) void*)(void*)(p))
#define AS3(p) ((__attribute__((address_space(3))) void*)(p))

// ---------------- generic bf16 GEMM: C = A[MxK] * B^T[NxK] ----------------
// MODE 0: C bf16 = acc*scale
// MODE 1: C bf16 = gelu(acc + bias[col])
// MODE 2: C f32  = acc + bias[col] + resid[row,col]
// BM: 128 (waves 2x2, 64x64 each) or 64 (waves 2x2 as 32x64 each, 64x128 tile)
template<int MODE, int BM>
__global__ __launch_bounds__(256) void gemm_bt(
    const short* __restrict__ A, int lda,
    const short* __restrict__ B, int ldb,
    void* __restrict__ Cv, int ldc,
    const float* __restrict__ bias, const float* __restrict__ resid,
    int M, int N, int K, int ntn, float scale)
{
    constexpr int MF = (BM == 128) ? 4 : 2;
    __shared__ short As[BM * 32];
    __shared__ short Bs[128 * 32];

    const int tm = (blockIdx.x / ntn) * BM;
    const int tn = (blockIdx.x % ntn) * 128;

    const int tid = threadIdx.x;
    const int w = tid >> 6, l = tid & 63;
    const int lane16 = l & 15, kg = l >> 4;
    const int wr = (BM == 128) ? (w >> 1) * 64 : (w & 1) * 32;
    const int wc = (BM == 128) ? (w & 1) * 64 : (w >> 1) * 64;

    f32x4 acc[MF][4] = {};

    for (int k0 = 0; k0 < K; k0 += 32) {
        if constexpr (BM == 128) {
            const int lr = l >> 2, lc = l & 3;
            #pragma unroll
            for (int i = 0; i < 2; ++i) {
                int row = (i * 4 + w) * 16 + lr;
                int ga = tm + row; if (ga > M - 1) ga = M - 1;
                const short* srca = A + (long)ga * lda + k0 + lc * 8;
                __builtin_amdgcn_global_load_lds(AS1(srca), AS3(As + (i * 4 + w) * 512), 16, 0, 0);
                int gb = tn + row; if (gb > N - 1) gb = N - 1;
                const short* srcb = B + (long)gb * ldb + k0 + lc * 8;
                __builtin_amdgcn_global_load_lds(AS1(srcb), AS3(Bs + (i * 4 + w) * 512), 16, 0, 0);
            }
        } else {
            const int lr = l >> 2, lc = l & 3;
            {   // A: 64 rows x 32 k = 4 KB, one issue
                int row = w * 16 + lr;
                int ga = tm + row; if (ga > M - 1) ga = M - 1;
                const short* srca = A + (long)ga * lda + k0 + lc * 8;
                __builtin_amdgcn_global_load_lds(AS1(srca), AS3(As + w * 512), 16, 0, 0);
            }
            #pragma unroll
            for (int i = 0; i < 2; ++i) {  // B: 128 rows = 8 KB, two issues
                int row = i * 64 + w * 16 + lr;
                int gb = tn + row; if (gb > N - 1) gb = N - 1;
                const short* srcb = B + (long)gb * ldb + k0 + lc * 8;
                __builtin_amdgcn_global_load_lds(AS1(srcb), AS3(Bs + i * 2048 + w * 512), 16, 0, 0);
            }
        }
        __syncthreads();

        bf16x8 af[MF], bfr[4];
        #pragma unroll
        for (int m = 0; m < MF; ++m)
            af[m] = *(const bf16x8*)(As + (wr + m * 16 + lane16) * 32 + kg * 8);
        #pragma unroll
        for (int n = 0; n < 4; ++n)
            bfr[n] = *(const bf16x8*)(Bs + (wc + n * 16 + lane16) * 32 + kg * 8);
        #pragma unroll
        for (int m = 0; m < MF; ++m)
            #pragma unroll
            for (int n = 0; n < 4; ++n)
                acc[m][n] = __builtin_amdgcn_mfma_f32_16x16x32_bf16(af[m], bfr[n], acc[m][n], 0, 0, 0);
        __syncthreads();
    }

    // ---- epilogue ----
    if (MODE == 2) {
        float* C = (float*)Cv;
        #pragma unroll
        for (int m = 0; m < MF; ++m)
            #pragma unroll
            for (int n = 0; n < 4; ++n) {
                int col = tn + wc + n * 16 + lane16;
                if (col >= N) continue;
                #pragma unroll
                for (int r = 0; r < 4; ++r) {
                    int row = tm + wr + m * 16 + kg * 4 + r;
                    if (row >= M) continue;
                    long idx = (long)row * ldc + col;
                    C[idx] = acc[m][n][r] * scale + bias[col] + resid[idx];
                }
            }
    } else {
        short* C = (short*)Cv;
        #pragma unroll
        for (int m = 0; m < MF; ++m)
            #pragma unroll
            for (int n = 0; n < 4; ++n) {
                int col = tn + wc + n * 16 + lane16;
                if (col >= N) continue;
                #pragma unroll
                for (int r = 0; r < 4; ++r) {
                    int row = tm + wr + m * 16 + kg * 4 + r;
                    if (row >= M) continue;
                    float v = acc[m][n][r] * scale;
                    if (MODE == 1) {
                        v += bias[col];
                        v = 0.5f * v * (1.0f + erff(v * 0.7071067811865476f));
                    }
                    C[(long)row * ldc + col] = f2bf(v);
                }
            }
    }
}

// ---------------- fused flash attention ----------------
// grid (B*H, N/128), block 512 (8 waves x 16 q-rows). KV tiled by 64, double-buffered.
// Q,K row-major bf16 [n][d] with row stride ldq/ldk, head col offset h*64.
// Vt: [z][64][1024] bf16 (d-major). O: [b*1024+q][1024] at col h*64.
__global__ __launch_bounds__(512) void flash_attn(
    const short* __restrict__ Q, int ldq, long sQb,
    const short* __restrict__ K, int ldk, long sKb,
    const short* __restrict__ Vt,
    short* __restrict__ O, int ldo, long sOb)
{
    __shared__ short Ks[2][64 * 64];   // [kv 64][d 64], 128B rows, chunk-swizzled
    __shared__ short Vts[2][64 * 64];  // [d 64][m 64], 128B rows, chunk-swizzled
    __shared__ short Ps[8][16 * 72];   // per-wave P tile [16 q][64 kv], pad to 72

    const int z = blockIdx.x;
    const int b = z >> 4, h = z & 15;
    const int qt = blockIdx.y;

    const int tid = threadIdx.x;
    const int w = tid >> 6, l = tid & 63;
    const int lane16 = l & 15, kg = l >> 4;

    const short* Qg = Q + sQb * b + h * 64;
    const short* Kg = K + sKb * b + h * 64;
    const short* Vtg = Vt + (long)z * 65536;
    short* Og = O + sOb * b + h * 64 + (long)(qt * 128 + w * 16) * ldo;

    // staging geometry: lane stages 16B at LDS byte (w*1024 + l*16)
    const int srow = w * 8 + (l >> 3);            // row 0..63 (128B rows)
    const int schunk = (l & 7) ^ (srow & 7);      // swizzled source chunk

    // Q fragments (row = lane16 of wave's 16-row strip)
    bf16x8 aq[2];
    {
        const short* qp = Qg + (long)(qt * 128 + w * 16 + lane16) * ldq + kg * 8;
        aq[0] = *(const bf16x8*)(qp);
        aq[1] = *(const bf16x8*)(qp + 32);
    }

    f32x4 acc_o[4] = {};
    float m_run[4], l_run[4];
    #pragma unroll
    for (int r = 0; r < 4; ++r) { m_run[r] = -1e30f; l_run[r] = 0.f; }

    short* Pw = (short*)Ps + w * (16 * 72);

    // prologue: stage tile 0 into buffer 0
    {
        const short* srck = Kg + (long)srow * ldk + schunk * 8;
        __builtin_amdgcn_global_load_lds(AS1(srck), AS3((short*)Ks + w * 512), 16, 0, 0);
        const short* srcv = Vtg + (long)srow * 1024 + schunk * 8;
        __builtin_amdgcn_global_load_lds(AS1(srcv), AS3((short*)Vts + w * 512), 16, 0, 0);
    }

    int cur = 0;
    for (int t = 0; t < 16; ++t) {
        __syncthreads();  // buf[cur] ready
        if (t < 15) {     // issue next tile into buf[cur^1]; drained at next barrier
            const short* srck = Kg + (long)((t + 1) * 64 + srow) * ldk + schunk * 8;
            __builtin_amdgcn_global_load_lds(AS1(srck), AS3((short*)Ks + (cur ^ 1) * 4096 + w * 512), 16, 0, 0);
            const short* srcv = Vtg + (long)srow * 1024 + (t + 1) * 64 + schunk * 8;
            __builtin_amdgcn_global_load_lds(AS1(srcv), AS3((short*)Vts + (cur ^ 1) * 4096 + w * 512), 16, 0, 0);
        }
        const short* Kb = (const short*)Ks + cur * 4096;
        const short* Vb = (const short*)Vts + cur * 4096;

        // ---- S = Q K^T  (rows q=kg*4+r, cols kv=16n+lane16) ----
        f32x4 acc_s[4] = {};
        #pragma unroll
        for (int n = 0; n < 4; ++n) {
            int row = 16 * n + lane16;
            #pragma unroll
            for (int ks = 0; ks < 2; ++ks) {
                bf16x8 bk = *(const bf16x8*)(Kb + row * 64 + (((ks * 4 + kg) ^ (row & 7)) * 8));
                acc_s[n] = __builtin_amdgcn_mfma_f32_16x16x32_bf16(aq[ks], bk, acc_s[n], 0, 0, 0);
            }
        }

        // ---- online softmax (wave-local; stats per r across lane16 groups) ----
        float mt[4], p[4][4], rs[4], mnew[4], corr[4];
        #pragma unroll
        for (int n = 0; n < 4; ++n)
            #pragma unroll
            for (int r = 0; r < 4; ++r) acc_s[n][r] *= 0.125f;
        #pragma unroll
        for (int r = 0; r < 4; ++r)
            mt[r] = fmaxf(fmaxf(acc_s[0][r], acc_s[1][r]), fmaxf(acc_s[2][r], acc_s[3][r]));
        #pragma unroll
        for (int off = 1; off < 16; off <<= 1)
            #pragma unroll
            for (int r = 0; r < 4; ++r) mt[r] = fmaxf(mt[r], __shfl_xor(mt[r], off));
        #pragma unroll
        for (int r = 0; r < 4; ++r) {
            mnew[r] = fmaxf(m_run[r], mt[r]);
            corr[r] = __expf(m_run[r] - mnew[r]);
            m_run[r] = mnew[r];
            rs[r] = 0.f;
        }
        #pragma unroll
        for (int n = 0; n < 4; ++n)
            #pragma unroll
            for (int r = 0; r < 4; ++r) {
                float e = __expf(acc_s[n][r] - mnew[r]);
                p[n][r] = e; rs[r] += e;
            }
        #pragma unroll
        for (int off = 1; off < 16; off <<= 1)
            #pragma unroll
            for (int r = 0; r < 4; ++r) rs[r] += __shfl_xor(rs[r], off);
        #pragma unroll
        for (int r = 0; r < 4; ++r) {
            l_run[r] = l_run[r] * corr[r] + rs[r];
            #pragma unroll
            for (int nd = 0; nd < 4; ++nd) acc_o[nd][r] *= corr[r];
        }

        // ---- P -> LDS (bf16, row-major [q][kv], stride 72) ----
        #pragma unroll
        for (int n = 0; n < 4; ++n)
            #pragma unroll
            for (int r = 0; r < 4; ++r)
                Pw[(kg * 4 + r) * 72 + 16 * n + lane16] = f2bf(p[n][r]);

        // ---- O += P V  (A = P frags, B = Vt frags) ----
        #pragma unroll
        for (int kk = 0; kk < 2; ++kk) {
            bf16x8 pa = *(const bf16x8*)(Pw + lane16 * 72 + kk * 32 + kg * 8);
            #pragma unroll
            for (int nd = 0; nd < 4; ++nd) {
                int d = 16 * nd + lane16;
                bf16x8 bv = *(const bf16x8*)(Vb + d * 64 + (((kk * 4 + kg) ^ (d & 7)) * 8));
                acc_o[nd] = __builtin_amdgcn_mfma_f32_16x16x32_bf16(pa, bv, acc_o[nd], 0, 0, 0);
            }
        }
        cur ^= 1;
    }

    // ---- epilogue: O / l ----
    #pragma unroll
    for (int r = 0; r < 4; ++r) {
        float inv = 1.0f / l_run[r];
        #pragma unroll
        for (int nd = 0; nd < 4; ++nd)
            Og[(long)(kg * 4 + r) * ldo + nd * 16 + lane16] = f2bf(acc_o[nd][r] * inv);
    }
}

// ---------------- LayerNorm fp32 -> bf16 (one block per row of 1024) ----------------
__global__ __launch_bounds__(256) void ln_bf16(const float* __restrict__ x,
                                               const float* __restrict__ g,
                                               const float* __restrict__ b,
                                               short* __restrict__ h)
{
    const long row = blockIdx.x;
    const int tid = threadIdx.x;
    float4 v = ((const float4*)(x + row * 1024))[tid];
    float s  = v.x + v.y + v.z + v.w;
    float s2 = v.x * v.x + v.y * v.y + v.z * v.z + v.w * v.w;
    #pragma unroll
    for (int off = 1; off < 64; off <<= 1) {
        s  += __shfl_xor(s, off);
        s2 += __shfl_xor(s2, off);
    }
    __shared__ float rs[4], rs2[4];
    int w = tid >> 6;
    if ((tid & 63) == 0) { rs[w] = s; rs2[w] = s2; }
    __syncthreads();
    s  = rs[0] + rs[1] + rs[2] + rs[3];
    s2 = rs2[0] + rs2[1] + rs2[2] + rs2[3];
    float mu  = s * (1.0f / 1024.0f);
    float var = s2 * (1.0f / 1024.0f) - mu * mu;
    float inv = rsqrtf(var + 1e-5f);
    float4 gv = ((const float4*)g)[tid];
    float4 bv = ((const float4*)b)[tid];
    short4v o;
    o[0] = f2bf((v.x - mu) * inv * gv.x + bv.x);
    o[1] = f2bf((v.y - mu) * inv * gv.y + bv.y);
    o[2] = f2bf((v.z - mu) * inv * gv.z + bv.z);
    o[3] = f2bf((v.w - mu) * inv * gv.w + bv.w);
    ((short4v*)(h + row * 1024))[tid] = o;
}

// ---------------- transpose fp32 [R][C] -> bf16 [C][R] ----------------
__global__ __launch_bounds__(256) void wconv_t(const float* __restrict__ in,
                                               short* __restrict__ out, int R, int C)
{
    __shared__ float t[32][33];
    const int c0 = blockIdx.x * 32, r0 = blockIdx.y * 32;
    const int tx = threadIdx.x & 31, ty = threadIdx.x >> 5;
    #pragma unroll
    for (int i = 0; i < 4; ++i)
        t[ty + i * 8][tx] = in[(long)(r0 + ty + i * 8) * C + c0 + tx];
    __syncthreads();
    #pragma unroll
    for (int i = 0; i < 4; ++i)
        out[(long)(c0 + ty + i * 8) * R + r0 + tx] = f2bf(t[tx][ty + i * 8]);
}

// ---------------- per-head V transpose: bf16 [m][d] -> vt[z][d][m] ----------------
__global__ __launch_bounds__(256) void vtrans(const short* __restrict__ src, int ld, int col_off,
                                              short* __restrict__ vt)
{
    __shared__ short t[32][33];
    const int z = blockIdx.z, bb = z >> 4, hh = z & 15;
    const int m0 = blockIdx.x * 32, d0 = blockIdx.y * 32;
    const int tx = threadIdx.x & 31, ty = threadIdx.x >> 5;
    const short* sp = src + (long)(bb * 1024) * ld + col_off + hh * 64;
    #pragma unroll
    for (int i = 0; i < 4; ++i)
        t[ty + i * 8][tx] = sp[(long)(m0 + ty + i * 8) * ld + d0 + tx];
    __syncthreads();
    short* op = vt + (long)z * 64 * 1024;
    #pragma unroll
    for (int i = 0; i < 4; ++i)
        op[(long)(d0 + ty + i * 8) * 1024 + m0 + tx] = t[tx][ty + i * 8];
}

// ---------------- elementwise fp32 -> bf16 ----------------
__global__ __launch_bounds__(256) void f2bf_vec(const float* __restrict__ in,
                                                short* __restrict__ out, int n4)
{
    int i = blockIdx.x * 256 + threadIdx.x;
    if (i < n4) {
        float4 v = ((const float4*)in)[i];
        short4v o;
        o[0] = f2bf(v.x); o[1] = f2bf(v.y); o[2] = f2bf(v.z); o[3] = f2bf(v.w);
        ((short4v*)out)[i] = o;
    }
}

// ---------------- host side ----------------
template<int MODE, int BM>
static void launch_gemm(const short* A, int lda, const short* B, int ldb,
                        void* C, int ldc, const float* bias, const float* resid,
                        int M, int N, int K, float scale, hipStream_t stream)
{
    int ntm = (M + BM - 1) / BM, ntn = (N + 127) / 128;
    dim3 grid(ntm * ntn);
    gemm_bt<MODE, BM><<<grid, 256, 0, stream>>>(A, lda, B, ldb, C, ldc, bias, resid,
                                                M, N, K, ntn, scale);
}

extern "C" void kernel_launch(void* const* d_in, const int* in_sizes, int n_in,
                              void* d_out, int out_size, void* d_ws, size_t ws_size,
                              hipStream_t stream)
{
    const float* x_in  = (const float*)d_in[0];
    const float* ctx   = (const float*)d_in[1];
    const float* ln1_g = (const float*)d_in[2];
    const float* ln1_b = (const float*)d_in[3];
    const float* w_qkv = (const float*)d_in[4];
    const float* w_o1  = (const float*)d_in[5];
    const float* b_o1  = (const float*)d_in[6];
    const float* ln2_g = (const float*)d_in[7];
    const float* ln2_b = (const float*)d_in[8];
    const float* w_q   = (const float*)d_in[9];
    const float* w_k   = (const float*)d_in[10];
    const float* w_v   = (const float*)d_in[11];
    const float* w_o2  = (const float*)d_in[12];
    const float* b_o2  = (const float*)d_in[13];
    const float* ln3_g = (const float*)d_in[14];
    const float* ln3_b = (const float*)d_in[15];
    const float* w_ff1 = (const float*)d_in[16];
    const float* b_ff1 = (const float*)d_in[17];
    const float* w_ff2 = (const float*)d_in[18];
    const float* b_ff2 = (const float*)d_in[19];
    float* xo = (float*)d_out;

    char* p = (char*)d_ws;
    short* wbuf   = (short*)(p);              // 8 MB (max 4096x1024 bf16)
    short* hbuf   = (short*)(p + 8388608);    // 4 MB
    short* qkvbuf = (short*)(p + 12582912);   // 12.58 MB
    short* vt     = (short*)(p + 92274688);   // 4 MB
    short* aout   = (short*)(p + 96468992);   // 4 MB
    short* ffbuf  = (short*)(p + 100663296);  // 16 MB
    short* ctxbuf = (short*)(p + 117440512);  // 4 MB

    hipMemcpyAsync(xo, x_in, (size_t)2 * 1024 * 1024 * 4, hipMemcpyDeviceToDevice, stream);
    f2bf_vec<<<2048, 256, 0, stream>>>(ctx, ctxbuf, 2 * 1024 * 1024 / 4);

    for (int l = 0; l < 2; ++l) {
        // ======== self attention ========
        ln_bf16<<<2048, 256, 0, stream>>>(xo, ln1_g + l * 1024, ln1_b + l * 1024, hbuf);
        wconv_t<<<dim3(96, 32), 256, 0, stream>>>(w_qkv + (long)l * 1024 * 3072, wbuf, 1024, 3072);
        launch_gemm<0, 128>(hbuf, 1024, wbuf, 1024, qkvbuf, 3072,
                            nullptr, nullptr, 2048, 3072, 1024, 1.0f, stream);
        vtrans<<<dim3(32, 2, 32), 256, 0, stream>>>(qkvbuf, 3072, 2048, vt);
        flash_attn<<<dim3(32, 8), 512, 0, stream>>>(qkvbuf, 3072, 3145728L,
                                                    qkvbuf + 1024, 3072, 3145728L,
                                                    vt, aout, 1024, 1048576L);
        wconv_t<<<dim3(32, 32), 256, 0, stream>>>(w_o1 + (long)l * 1048576, wbuf, 1024, 1024);
        launch_gemm<2, 64>(aout, 1024, wbuf, 1024, xo, 1024,
                           b_o1 + l * 1024, xo, 2048, 1024, 1024, 1.0f, stream);

        // ======== cross attention ========
        ln_bf16<<<2048, 256, 0, stream>>>(xo, ln2_g + l * 1024, ln2_b + l * 1024, hbuf);
        short* q2 = qkvbuf;
        short* k2 = qkvbuf + 2048 * 1024;
        short* v2 = qkvbuf + 2 * 2048 * 1024;
        wconv_t<<<dim3(32, 32), 256, 0, stream>>>(w_q + (long)l * 1048576, wbuf, 1024, 1024);
        launch_gemm<0, 64>(hbuf, 1024, wbuf, 1024, q2, 1024,
                           nullptr, nullptr, 2048, 1024, 1024, 1.0f, stream);
        wconv_t<<<dim3(32, 32), 256, 0, stream>>>(w_k + (long)l * 1048576, wbuf, 1024, 1024);
        launch_gemm<0, 64>(ctxbuf, 1024, wbuf, 1024, k2, 1024,
                           nullptr, nullptr, 2048, 1024, 1024, 1.0f, stream);
        wconv_t<<<dim3(32, 32), 256, 0, stream>>>(w_v + (long)l * 1048576, wbuf, 1024, 1024);
        launch_gemm<0, 64>(ctxbuf, 1024, wbuf, 1024, v2, 1024,
                           nullptr, nullptr, 2048, 1024, 1024, 1.0f, stream);
        vtrans<<<dim3(32, 2, 32), 256, 0, stream>>>(v2, 1024, 0, vt);
        flash_attn<<<dim3(32, 8), 512, 0, stream>>>(q2, 1024, 1048576L,
                                                    k2, 1024, 1048576L,
                                                    vt, aout, 1024, 1048576L);
        wconv_t<<<dim3(32, 32), 256, 0, stream>>>(w_o2 + (long)l * 1048576, wbuf, 1024, 1024);
        launch_gemm<2, 64>(aout, 1024, wbuf, 1024, xo, 1024,
                           b_o2 + l * 1024, xo, 2048, 1024, 1024, 1.0f, stream);

        // ======== FFN ========
        ln_bf16<<<2048, 256, 0, stream>>>(xo, ln3_g + l * 1024, ln3_b + l * 1024, hbuf);
        wconv_t<<<dim3(128, 32), 256, 0, stream>>>(w_ff1 + (long)l * 1024 * 4096, wbuf, 1024, 4096);
        launch_gemm<1, 128>(hbuf, 1024, wbuf, 1024, ffbuf, 4096,
                            b_ff1 + l * 4096, nullptr, 2048, 4096, 1024, 1.0f, stream);
        wconv_t<<<dim3(32, 128), 256, 0, stream>>>(w_ff2 + (long)l * 4096 * 1024, wbuf, 4096, 1024);
        launch_gemm<2, 64>(ffbuf, 4096, wbuf, 4096, xo, 1024,
                           b_ff2 + l * 1024, xo, 2048, 1024, 4096, 1.0f, stream);
    }
}

// Round 6
// 876.687 us; speedup vs baseline: 1.4591x; 1.0386x over previous
//
#include <hip/hip_runtime.h>

// ---------------- types / helpers ----------------
typedef __attribute__((ext_vector_type(8))) short bf16x8;
typedef __attribute__((ext_vector_type(4))) short short4v;
typedef __attribute__((ext_vector_type(4))) float f32x4;

__device__ __forceinline__ float bf2f(short s) {
    union { unsigned u; float f; } c;
    c.u = ((unsigned)(unsigned short)s) << 16;
    return c.f;
}
__device__ __forceinline__ short f2bf(float f) {
    union { float f; unsigned u; } c; c.f = f;
    unsigned r = (c.u + 0x7fffu + ((c.u >> 16) & 1u)) >> 16;
    return (short)r;
}

#define AS1(p) ((__attribute__((address_space(1))) void*)(void*)(p))
#define AS3(p) ((__attribute__((address_space(3))) void*)(p))

// ---------------- pipelined bf16 GEMM: C = A[MxK] * B^T[NxK] ----------------
// BK=64, 3 LDS buffers, 2 tiles in flight (counted vmcnt), XOR-swizzled LDS.
// MODE 0: C bf16 = acc
// MODE 1: C bf16 = gelu(acc + bias[col])
// MODE 2: C f32  = acc + bias[col] + resid[row,col]
// BM=128: 4 waves as 2x2, wave tile 64x64.  BM=64: 4 waves as 2x2, wave tile 32x64.
template<int MODE, int BM>
__global__ __launch_bounds__(256) void gemm2(
    const short* __restrict__ A, int lda,
    const short* __restrict__ B, int ldb,
    void* __restrict__ Cv, int ldc,
    const float* __restrict__ bias, const float* __restrict__ resid,
    int ntn, int nt, float scale)
{
    constexpr int MF = (BM == 128) ? 4 : 2;
    constexpr int NIA = BM / 32;           // A stage issues (2 or 4)
    __shared__ short As[3][BM * 64];
    __shared__ short Bs[3][128 * 64];

    // XCD-chunked swizzle (requires gridDim.x % 8 == 0; all call sites comply)
    const int nwg = gridDim.x;
    const int bid = blockIdx.x;
    const int tile = (bid & 7) * (nwg >> 3) + (bid >> 3);

    const int tm = (tile / ntn) * BM;
    const int tn = (tile % ntn) * 128;

    const int tid = threadIdx.x;
    const int w = tid >> 6, l = tid & 63;
    const int lane16 = l & 15, kg = l >> 4;
    const int wr = (BM == 128) ? (w >> 1) * 64 : (w & 1) * 32;
    const int wc = (BM == 128) ? (w & 1) * 64 : (w >> 1) * 64;

    // staging pointers (advance by 64 shorts per staged tile)
    const short* pa[NIA];
    const short* pb[4];
    #pragma unroll
    for (int j = 0; j < NIA; ++j) {
        int row = (j * 4 + w) * 8 + (l >> 3);
        pa[j] = A + (long)(tm + row) * lda + (((l & 7) ^ (row & 7)) * 8);
    }
    #pragma unroll
    for (int j = 0; j < 4; ++j) {
        int row = (j * 4 + w) * 8 + (l >> 3);
        pb[j] = B + (long)(tn + row) * ldb + (((l & 7) ^ (row & 7)) * 8);
    }

    f32x4 acc[MF][4] = {};

    auto stage = [&](int buf) {
        #pragma unroll
        for (int j = 0; j < NIA; ++j) {
            __builtin_amdgcn_global_load_lds(AS1(pa[j]), AS3(&As[buf][(j * 4 + w) * 512]), 16, 0, 0);
            pa[j] += 64;
        }
        #pragma unroll
        for (int j = 0; j < 4; ++j) {
            __builtin_amdgcn_global_load_lds(AS1(pb[j]), AS3(&Bs[buf][(j * 4 + w) * 512]), 16, 0, 0);
            pb[j] += 64;
        }
    };

    auto compute = [&](int buf) {
        bf16x8 af[2][MF], bfr[2][4];
        #pragma unroll
        for (int kk = 0; kk < 2; ++kk) {
            int swz = ((kk * 4 + kg) ^ (lane16 & 7)) * 8;
            #pragma unroll
            for (int m = 0; m < MF; ++m)
                af[kk][m] = *(const bf16x8*)&As[buf][(wr + m * 16 + lane16) * 64 + swz];
            #pragma unroll
            for (int n = 0; n < 4; ++n)
                bfr[kk][n] = *(const bf16x8*)&Bs[buf][(wc + n * 16 + lane16) * 64 + swz];
        }
        #pragma unroll
        for (int kk = 0; kk < 2; ++kk)
            #pragma unroll
            for (int m = 0; m < MF; ++m)
                #pragma unroll
                for (int n = 0; n < 4; ++n)
                    acc[m][n] = __builtin_amdgcn_mfma_f32_16x16x32_bf16(af[kk][m], bfr[kk][n], acc[m][n], 0, 0, 0);
    };

    #define WAIT_VMCNT_L()  do { \
        if constexpr (BM == 64) asm volatile("s_waitcnt vmcnt(6)" ::: "memory"); \
        else                    asm volatile("s_waitcnt vmcnt(8)" ::: "memory"); \
        __builtin_amdgcn_sched_barrier(0); \
        __builtin_amdgcn_s_barrier(); \
        __builtin_amdgcn_sched_barrier(0); } while (0)

    // prologue: tiles 0 and 1 in flight; wait tile 0
    stage(0);
    stage(1);
    WAIT_VMCNT_L();

    for (int t = 0; t < nt - 2; ++t) {
        stage((t + 2) % 3);
        compute(t % 3);
        WAIT_VMCNT_L();
    }
    // t = nt-2: nothing left to stage; drain tile nt-1
    compute((nt - 2) % 3);
    asm volatile("s_waitcnt vmcnt(0)" ::: "memory");
    __builtin_amdgcn_sched_barrier(0);
    __builtin_amdgcn_s_barrier();
    __builtin_amdgcn_sched_barrier(0);
    compute((nt - 1) % 3);
    #undef WAIT_VMCNT_L

    // ---- epilogue ----
    if (MODE == 2) {
        float* C = (float*)Cv;
        #pragma unroll
        for (int m = 0; m < MF; ++m)
            #pragma unroll
            for (int n = 0; n < 4; ++n) {
                int col = tn + wc + n * 16 + lane16;
                #pragma unroll
                for (int r = 0; r < 4; ++r) {
                    int row = tm + wr + m * 16 + kg * 4 + r;
                    long idx = (long)row * ldc + col;
                    C[idx] = acc[m][n][r] * scale + bias[col] + resid[idx];
                }
            }
    } else {
        short* C = (short*)Cv;
        #pragma unroll
        for (int m = 0; m < MF; ++m)
            #pragma unroll
            for (int n = 0; n < 4; ++n) {
                int col = tn + wc + n * 16 + lane16;
                #pragma unroll
                for (int r = 0; r < 4; ++r) {
                    int row = tm + wr + m * 16 + kg * 4 + r;
                    float v = acc[m][n][r] * scale;
                    if (MODE == 1) {
                        v += bias[col];
                        v = 0.5f * v * (1.0f + erff(v * 0.7071067811865476f));
                    }
                    C[(long)row * ldc + col] = f2bf(v);
                }
            }
    }
}

// ---------------- fused flash attention ----------------
// grid (B*H, N/128), block 512 (8 waves x 16 q-rows). KV tiled by 64, double-buffered.
__global__ __launch_bounds__(512) void flash_attn(
    const short* __restrict__ Q, int ldq, long sQb,
    const short* __restrict__ K, int ldk, long sKb,
    const short* __restrict__ Vt,
    short* __restrict__ O, int ldo, long sOb)
{
    __shared__ short Ks[2][64 * 64];
    __shared__ short Vts[2][64 * 64];
    __shared__ short Ps[8][16 * 72];

    const int z = blockIdx.x;
    const int b = z >> 4, h = z & 15;
    const int qt = blockIdx.y;

    const int tid = threadIdx.x;
    const int w = tid >> 6, l = tid & 63;
    const int lane16 = l & 15, kg = l >> 4;

    const short* Qg = Q + sQb * b + h * 64;
    const short* Kg = K + sKb * b + h * 64;
    const short* Vtg = Vt + (long)z * 65536;
    short* Og = O + sOb * b + h * 64 + (long)(qt * 128 + w * 16) * ldo;

    const int srow = w * 8 + (l >> 3);
    const int schunk = (l & 7) ^ (srow & 7);

    bf16x8 aq[2];
    {
        const short* qp = Qg + (long)(qt * 128 + w * 16 + lane16) * ldq + kg * 8;
        aq[0] = *(const bf16x8*)(qp);
        aq[1] = *(const bf16x8*)(qp + 32);
    }

    f32x4 acc_o[4] = {};
    float m_run[4], l_run[4];
    #pragma unroll
    for (int r = 0; r < 4; ++r) { m_run[r] = -1e30f; l_run[r] = 0.f; }

    short* Pw = (short*)Ps + w * (16 * 72);

    {
        const short* srck = Kg + (long)srow * ldk + schunk * 8;
        __builtin_amdgcn_global_load_lds(AS1(srck), AS3((short*)Ks + w * 512), 16, 0, 0);
        const short* srcv = Vtg + (long)srow * 1024 + schunk * 8;
        __builtin_amdgcn_global_load_lds(AS1(srcv), AS3((short*)Vts + w * 512), 16, 0, 0);
    }

    int cur = 0;
    for (int t = 0; t < 16; ++t) {
        __syncthreads();
        if (t < 15) {
            const short* srck = Kg + (long)((t + 1) * 64 + srow) * ldk + schunk * 8;
            __builtin_amdgcn_global_load_lds(AS1(srck), AS3((short*)Ks + (cur ^ 1) * 4096 + w * 512), 16, 0, 0);
            const short* srcv = Vtg + (long)srow * 1024 + (t + 1) * 64 + schunk * 8;
            __builtin_amdgcn_global_load_lds(AS1(srcv), AS3((short*)Vts + (cur ^ 1) * 4096 + w * 512), 16, 0, 0);
        }
        const short* Kb = (const short*)Ks + cur * 4096;
        const short* Vb = (const short*)Vts + cur * 4096;

        f32x4 acc_s[4] = {};
        #pragma unroll
        for (int n = 0; n < 4; ++n) {
            int row = 16 * n + lane16;
            #pragma unroll
            for (int ks = 0; ks < 2; ++ks) {
                bf16x8 bk = *(const bf16x8*)(Kb + row * 64 + (((ks * 4 + kg) ^ (row & 7)) * 8));
                acc_s[n] = __builtin_amdgcn_mfma_f32_16x16x32_bf16(aq[ks], bk, acc_s[n], 0, 0, 0);
            }
        }

        float mt[4], p[4][4], rs[4], mnew[4], corr[4];
        #pragma unroll
        for (int n = 0; n < 4; ++n)
            #pragma unroll
            for (int r = 0; r < 4; ++r) acc_s[n][r] *= 0.125f;
        #pragma unroll
        for (int r = 0; r < 4; ++r)
            mt[r] = fmaxf(fmaxf(acc_s[0][r], acc_s[1][r]), fmaxf(acc_s[2][r], acc_s[3][r]));
        #pragma unroll
        for (int off = 1; off < 16; off <<= 1)
            #pragma unroll
            for (int r = 0; r < 4; ++r) mt[r] = fmaxf(mt[r], __shfl_xor(mt[r], off));
        #pragma unroll
        for (int r = 0; r < 4; ++r) {
            mnew[r] = fmaxf(m_run[r], mt[r]);
            corr[r] = __expf(m_run[r] - mnew[r]);
            m_run[r] = mnew[r];
            rs[r] = 0.f;
        }
        #pragma unroll
        for (int n = 0; n < 4; ++n)
            #pragma unroll
            for (int r = 0; r < 4; ++r) {
                float e = __expf(acc_s[n][r] - mnew[r]);
                p[n][r] = e; rs[r] += e;
            }
        #pragma unroll
        for (int off = 1; off < 16; off <<= 1)
            #pragma unroll
            for (int r = 0; r < 4; ++r) rs[r] += __shfl_xor(rs[r], off);
        #pragma unroll
        for (int r = 0; r < 4; ++r) {
            l_run[r] = l_run[r] * corr[r] + rs[r];
            #pragma unroll
            for (int nd = 0; nd < 4; ++nd) acc_o[nd][r] *= corr[r];
        }

        #pragma unroll
        for (int n = 0; n < 4; ++n)
            #pragma unroll
            for (int r = 0; r < 4; ++r)
                Pw[(kg * 4 + r) * 72 + 16 * n + lane16] = f2bf(p[n][r]);

        #pragma unroll
        for (int kk = 0; kk < 2; ++kk) {
            bf16x8 pa = *(const bf16x8*)(Pw + lane16 * 72 + kk * 32 + kg * 8);
            #pragma unroll
            for (int nd = 0; nd < 4; ++nd) {
                int d = 16 * nd + lane16;
                bf16x8 bv = *(const bf16x8*)(Vb + d * 64 + (((kk * 4 + kg) ^ (d & 7)) * 8));
                acc_o[nd] = __builtin_amdgcn_mfma_f32_16x16x32_bf16(pa, bv, acc_o[nd], 0, 0, 0);
            }
        }
        cur ^= 1;
    }

    #pragma unroll
    for (int r = 0; r < 4; ++r) {
        float inv = 1.0f / l_run[r];
        #pragma unroll
        for (int nd = 0; nd < 4; ++nd)
            Og[(long)(kg * 4 + r) * ldo + nd * 16 + lane16] = f2bf(acc_o[nd][r] * inv);
    }
}

// ---------------- LayerNorm fp32 -> bf16 ----------------
__global__ __launch_bounds__(256) void ln_bf16(const float* __restrict__ x,
                                               const float* __restrict__ g,
                                               const float* __restrict__ b,
                                               short* __restrict__ h)
{
    const long row = blockIdx.x;
    const int tid = threadIdx.x;
    float4 v = ((const float4*)(x + row * 1024))[tid];
    float s  = v.x + v.y + v.z + v.w;
    float s2 = v.x * v.x + v.y * v.y + v.z * v.z + v.w * v.w;
    #pragma unroll
    for (int off = 1; off < 64; off <<= 1) {
        s  += __shfl_xor(s, off);
        s2 += __shfl_xor(s2, off);
    }
    __shared__ float rs[4], rs2[4];
    int w = tid >> 6;
    if ((tid & 63) == 0) { rs[w] = s; rs2[w] = s2; }
    __syncthreads();
    s  = rs[0] + rs[1] + rs[2] + rs[3];
    s2 = rs2[0] + rs2[1] + rs2[2] + rs2[3];
    float mu  = s * (1.0f / 1024.0f);
    float var = s2 * (1.0f / 1024.0f) - mu * mu;
    float inv = rsqrtf(var + 1e-5f);
    float4 gv = ((const float4*)g)[tid];
    float4 bv = ((const float4*)b)[tid];
    short4v o;
    o[0] = f2bf((v.x - mu) * inv * gv.x + bv.x);
    o[1] = f2bf((v.y - mu) * inv * gv.y + bv.y);
    o[2] = f2bf((v.z - mu) * inv * gv.z + bv.z);
    o[3] = f2bf((v.w - mu) * inv * gv.w + bv.w);
    ((short4v*)(h + row * 1024))[tid] = o;
}

// ---------------- transpose fp32 [R][C] -> bf16 [C][R] ----------------
__global__ __launch_bounds__(256) void wconv_t(const float* __restrict__ in,
                                               short* __restrict__ out, int R, int C)
{
    __shared__ float t[32][33];
    const int c0 = blockIdx.x * 32, r0 = blockIdx.y * 32;
    const int tx = threadIdx.x & 31, ty = threadIdx.x >> 5;
    #pragma unroll
    for (int i = 0; i < 4; ++i)
        t[ty + i * 8][tx] = in[(long)(r0 + ty + i * 8) * C + c0 + tx];
    __syncthreads();
    #pragma unroll
    for (int i = 0; i < 4; ++i)
        out[(long)(c0 + ty + i * 8) * R + r0 + tx] = f2bf(t[tx][ty + i * 8]);
}

// ---------------- per-head V transpose: bf16 [m][d] -> vt[z][d][m] ----------------
__global__ __launch_bounds__(256) void vtrans(const short* __restrict__ src, int ld, int col_off,
                                              short* __restrict__ vt)
{
    __shared__ short t[32][33];
    const int z = blockIdx.z, bb = z >> 4, hh = z & 15;
    const int m0 = blockIdx.x * 32, d0 = blockIdx.y * 32;
    const int tx = threadIdx.x & 31, ty = threadIdx.x >> 5;
    const short* sp = src + (long)(bb * 1024) * ld + col_off + hh * 64;
    #pragma unroll
    for (int i = 0; i < 4; ++i)
        t[ty + i * 8][tx] = sp[(long)(m0 + ty + i * 8) * ld + d0 + tx];
    __syncthreads();
    short* op = vt + (long)z * 64 * 1024;
    #pragma unroll
    for (int i = 0; i < 4; ++i)
        op[(long)(d0 + ty + i * 8) * 1024 + m0 + tx] = t[tx][ty + i * 8];
}

// ---------------- elementwise fp32 -> bf16 ----------------
__global__ __launch_bounds__(256) void f2bf_vec(const float* __restrict__ in,
                                                short* __restrict__ out, int n4)
{
    int i = blockIdx.x * 256 + threadIdx.x;
    if (i < n4) {
        float4 v = ((const float4*)in)[i];
        short4v o;
        o[0] = f2bf(v.x); o[1] = f2bf(v.y); o[2] = f2bf(v.z); o[3] = f2bf(v.w);
        ((short4v*)out)[i] = o;
    }
}

// ---------------- host side ----------------
template<int MODE, int BM>
static void launch_gemm2(const short* A, int lda, const short* B, int ldb,
                         void* C, int ldc, const float* bias, const float* resid,
                         int M, int N, int K, hipStream_t stream)
{
    int ntm = M / BM, ntn = N / 128;
    gemm2<MODE, BM><<<dim3(ntm * ntn), 256, 0, stream>>>(A, lda, B, ldb, C, ldc,
                                                         bias, resid, ntn, K / 64, 1.0f);
}

extern "C" void kernel_launch(void* const* d_in, const int* in_sizes, int n_in,
                              void* d_out, int out_size, void* d_ws, size_t ws_size,
                              hipStream_t stream)
{
    const float* x_in  = (const float*)d_in[0];
    const float* ctx   = (const float*)d_in[1];
    const float* ln1_g = (const float*)d_in[2];
    const float* ln1_b = (const float*)d_in[3];
    const float* w_qkv = (const float*)d_in[4];
    const float* w_o1  = (const float*)d_in[5];
    const float* b_o1  = (const float*)d_in[6];
    const float* ln2_g = (const float*)d_in[7];
    const float* ln2_b = (const float*)d_in[8];
    const float* w_q   = (const float*)d_in[9];
    const float* w_k   = (const float*)d_in[10];
    const float* w_v   = (const float*)d_in[11];
    const float* w_o2  = (const float*)d_in[12];
    const float* b_o2  = (const float*)d_in[13];
    const float* ln3_g = (const float*)d_in[14];
    const float* ln3_b = (const float*)d_in[15];
    const float* w_ff1 = (const float*)d_in[16];
    const float* b_ff1 = (const float*)d_in[17];
    const float* w_ff2 = (const float*)d_in[18];
    const float* b_ff2 = (const float*)d_in[19];
    float* xo = (float*)d_out;

    char* p = (char*)d_ws;
    short* wbuf   = (short*)(p);              // 8 MB (max 4096x1024 bf16; also packed k|v weights)
    short* hbuf   = (short*)(p + 8388608);    // 4 MB
    short* qkvbuf = (short*)(p + 12582912);   // 12.58 MB
    short* k2v2   = (short*)(p + 25165824);   // 8 MB  [2048][2048]
    short* vt     = (short*)(p + 92274688);   // 4 MB
    short* aout   = (short*)(p + 96468992);   // 4 MB
    short* ffbuf  = (short*)(p + 100663296);  // 16 MB
    short* ctxbuf = (short*)(p + 117440512);  // 4 MB

    hipMemcpyAsync(xo, x_in, (size_t)2 * 1024 * 1024 * 4, hipMemcpyDeviceToDevice, stream);
    f2bf_vec<<<2048, 256, 0, stream>>>(ctx, ctxbuf, 2 * 1024 * 1024 / 4);

    for (int l = 0; l < 2; ++l) {
        // ======== self attention ========
        ln_bf16<<<2048, 256, 0, stream>>>(xo, ln1_g + l * 1024, ln1_b + l * 1024, hbuf);
        wconv_t<<<dim3(96, 32), 256, 0, stream>>>(w_qkv + (long)l * 1024 * 3072, wbuf, 1024, 3072);
        launch_gemm2<0, 128>(hbuf, 1024, wbuf, 1024, qkvbuf, 3072,
                             nullptr, nullptr, 2048, 3072, 1024, stream);
        vtrans<<<dim3(32, 2, 32), 256, 0, stream>>>(qkvbuf, 3072, 2048, vt);
        flash_attn<<<dim3(32, 8), 512, 0, stream>>>(qkvbuf, 3072, 3145728L,
                                                    qkvbuf + 1024, 3072, 3145728L,
                                                    vt, aout, 1024, 1048576L);
        wconv_t<<<dim3(32, 32), 256, 0, stream>>>(w_o1 + (long)l * 1048576, wbuf, 1024, 1024);
        launch_gemm2<2, 64>(aout, 1024, wbuf, 1024, xo, 1024,
                            b_o1 + l * 1024, xo, 2048, 1024, 1024, stream);

        // ======== cross attention ========
        ln_bf16<<<2048, 256, 0, stream>>>(xo, ln2_g + l * 1024, ln2_b + l * 1024, hbuf);
        short* q2 = qkvbuf;
        wconv_t<<<dim3(32, 32), 256, 0, stream>>>(w_q + (long)l * 1048576, wbuf, 1024, 1024);
        launch_gemm2<0, 64>(hbuf, 1024, wbuf, 1024, q2, 1024,
                            nullptr, nullptr, 2048, 1024, 1024, stream);
        // packed K|V weights -> one N=2048 GEMM from ctx
        wconv_t<<<dim3(32, 32), 256, 0, stream>>>(w_k + (long)l * 1048576, wbuf, 1024, 1024);
        wconv_t<<<dim3(32, 32), 256, 0, stream>>>(w_v + (long)l * 1048576, wbuf + 1048576, 1024, 1024);
        launch_gemm2<0, 64>(ctxbuf, 1024, wbuf, 1024, k2v2, 2048,
                            nullptr, nullptr, 2048, 2048, 1024, stream);
        vtrans<<<dim3(32, 2, 32), 256, 0, stream>>>(k2v2 + 1024, 2048, 0, vt);
        flash_attn<<<dim3(32, 8), 512, 0, stream>>>(q2, 1024, 1048576L,
                                                    k2v2, 2048, 2097152L,
                                                    vt, aout, 1024, 1048576L);
        wconv_t<<<dim3(32, 32), 256, 0, stream>>>(w_o2 + (long)l * 1048576, wbuf, 1024, 1024);
        launch_gemm2<2, 64>(aout, 1024, wbuf, 1024, xo, 1024,
                            b_o2 + l * 1024, xo, 2048, 1024, 1024, stream);

        // ======== FFN ========
        ln_bf16<<<2048, 256, 0, stream>>>(xo, ln3_g + l * 1024, ln3_b + l * 1024, hbuf);
        wconv_t<<<dim3(128, 32), 256, 0, stream>>>(w_ff1 + (long)l * 1024 * 4096, wbuf, 1024, 4096);
        launch_gemm2<1, 128>(hbuf, 1024, wbuf, 1024, ffbuf, 4096,
                             b_ff1 + l * 4096, nullptr, 2048, 4096, 1024, stream);
        wconv_t<<<dim3(32, 128), 256, 0, stream>>>(w_ff2 + (long)l * 4096 * 1024, wbuf, 4096, 1024);
        launch_gemm2<2, 64>(ffbuf, 4096, wbuf, 4096, xo, 1024,
                            b_ff2 + l * 1024, xo, 2048, 1024, 4096, stream);
    }
}

// Round 9
// 741.139 us; speedup vs baseline: 1.7260x; 1.1829x over previous
//
#include <hip/hip_runtime.h>

// ---------------- types / helpers ----------------
typedef __attribute__((ext_vector_type(8))) short bf16x8;
typedef __attribute__((ext_vector_type(4))) short short4v;
typedef __attribute__((ext_vector_type(4))) float f32x4;

__device__ __forceinline__ float bf2f(short s) {
    union { unsigned u; float f; } c;
    c.u = ((unsigned)(unsigned short)s) << 16;
    return c.f;
}
__device__ __forceinline__ short f2bf(float f) {
    union { float f; unsigned u; } c; c.f = f;
    unsigned r = (c.u + 0x7fffu + ((c.u >> 16) & 1u)) >> 16;
    return (short)r;
}

#define AS1(p) ((__attribute__((address_space(1))) void*)(void*)(p))
#define AS3(p) ((__attribute__((address_space(3))) void*)(p))

// ---------------- 2-phase pipelined bf16 GEMM: C = A[MxK] * B^T[NxK] -------
// BK=64, 2 LDS buffers: stage(t+1) -> compute(t) -> vmcnt(0)+barrier.
// LDS: BM=128 -> 64KB (2 blocks/CU), BM=64 -> 48KB (3 blocks/CU).
// 2D super-tile XCD mapping: each XCD owns an 8m x (nwg/64)n rectangle.
// MODE 0: C bf16 = acc ; MODE 1: bf16 gelu(acc+bias) ; MODE 2: f32 acc+bias+resid
template<int MODE, int BM>
__global__ __launch_bounds__(256) void gemm2(
    const short* __restrict__ A, int lda,
    const short* __restrict__ B, int ldb,
    void* __restrict__ Cv, int ldc,
    const float* __restrict__ bias, const float* __restrict__ resid,
    int ntn, int nt, float scale)
{
    constexpr int MF = (BM == 128) ? 4 : 2;
    constexpr int NIA = BM / 32;           // A stage issues per tile
    __shared__ short As[2][BM * 64];
    __shared__ short Bs[2][128 * 64];

    // XCD chunk (contiguous r range per XCD), then 8-row super-tile:
    // requires gridDim.x % 8 == 0 and ntm % 8 == 0 (all call sites comply).
    const int nwg = gridDim.x;
    const int bid = blockIdx.x;
    const int r = (bid & 7) * (nwg >> 3) + (bid >> 3);
    const int span = 8 * ntn;
    const int g = r / span, rem = r % span;
    const int tm = (g * 8 + (rem & 7)) * BM;
    const int tn = (rem >> 3) * 128;

    const int tid = threadIdx.x;
    const int w = tid >> 6, l = tid & 63;
    const int lane16 = l & 15, kg = l >> 4;
    const int wr = (BM == 128) ? (w >> 1) * 64 : (w & 1) * 32;
    const int wc = (BM == 128) ? (w & 1) * 64 : (w >> 1) * 64;

    // staging pointers (advance by 64 shorts per staged tile)
    const short* pa[NIA];
    const short* pb[4];
    #pragma unroll
    for (int j = 0; j < NIA; ++j) {
        int row = (j * 4 + w) * 8 + (l >> 3);
        pa[j] = A + (long)(tm + row) * lda + (((l & 7) ^ (row & 7)) * 8);
    }
    #pragma unroll
    for (int j = 0; j < 4; ++j) {
        int row = (j * 4 + w) * 8 + (l >> 3);
        pb[j] = B + (long)(tn + row) * ldb + (((l & 7) ^ (row & 7)) * 8);
    }

    f32x4 acc[MF][4] = {};

    auto stage = [&](int buf) {
        #pragma unroll
        for (int j = 0; j < NIA; ++j) {
            __builtin_amdgcn_global_load_lds(AS1(pa[j]), AS3(&As[buf][(j * 4 + w) * 512]), 16, 0, 0);
            pa[j] += 64;
        }
        #pragma unroll
        for (int j = 0; j < 4; ++j) {
            __builtin_amdgcn_global_load_lds(AS1(pb[j]), AS3(&Bs[buf][(j * 4 + w) * 512]), 16, 0, 0);
            pb[j] += 64;
        }
    };

    auto compute = [&](int buf) {
        bf16x8 af[2][MF], bfr[2][4];
        #pragma unroll
        for (int kk = 0; kk < 2; ++kk) {
            int swz = ((kk * 4 + kg) ^ (lane16 & 7)) * 8;
            #pragma unroll
            for (int m = 0; m < MF; ++m)
                af[kk][m] = *(const bf16x8*)&As[buf][(wr + m * 16 + lane16) * 64 + swz];
            #pragma unroll
            for (int n = 0; n < 4; ++n)
                bfr[kk][n] = *(const bf16x8*)&Bs[buf][(wc + n * 16 + lane16) * 64 + swz];
        }
        #pragma unroll
        for (int kk = 0; kk < 2; ++kk)
            #pragma unroll
            for (int m = 0; m < MF; ++m)
                #pragma unroll
                for (int n = 0; n < 4; ++n)
                    acc[m][n] = __builtin_amdgcn_mfma_f32_16x16x32_bf16(af[kk][m], bfr[kk][n], acc[m][n], 0, 0, 0);
    };

    #define SYNC_TILE() do { \
        asm volatile("s_waitcnt vmcnt(0)" ::: "memory"); \
        __builtin_amdgcn_sched_barrier(0); \
        __builtin_amdgcn_s_barrier(); \
        __builtin_amdgcn_sched_barrier(0); } while (0)

    stage(0);
    SYNC_TILE();
    for (int t = 0; t < nt; ++t) {
        if (t + 1 < nt) stage((t + 1) & 1);   // safe: barrier at end of t-1 cleared this buf
        compute(t & 1);                        // overlaps the in-flight stage
        if (t + 1 < nt) SYNC_TILE();           // next buf ready; this buf released
    }
    #undef SYNC_TILE

    // ---- epilogue ----
    if (MODE == 2) {
        float* C = (float*)Cv;
        #pragma unroll
        for (int m = 0; m < MF; ++m)
            #pragma unroll
            for (int n = 0; n < 4; ++n) {
                int col = tn + wc + n * 16 + lane16;
                #pragma unroll
                for (int r2 = 0; r2 < 4; ++r2) {
                    int row = tm + wr + m * 16 + kg * 4 + r2;
                    long idx = (long)row * ldc + col;
                    C[idx] = acc[m][n][r2] * scale + bias[col] + resid[idx];
                }
            }
    } else {
        short* C = (short*)Cv;
        #pragma unroll
        for (int m = 0; m < MF; ++m)
            #pragma unroll
            for (int n = 0; n < 4; ++n) {
                int col = tn + wc + n * 16 + lane16;
                #pragma unroll
                for (int r2 = 0; r2 < 4; ++r2) {
                    int row = tm + wr + m * 16 + kg * 4 + r2;
                    float v = acc[m][n][r2] * scale;
                    if (MODE == 1) {
                        v += bias[col];
                        v = 0.5f * v * (1.0f + erff(v * 0.7071067811865476f));
                    }
                    C[(long)row * ldc + col] = f2bf(v);
                }
            }
    }
}

// ---------------- fused flash attention ----------------
// grid (B*H, N/128), block 512 (8 waves x 16 q-rows). KV tiled by 64, double-buffered.
__global__ __launch_bounds__(512) void flash_attn(
    const short* __restrict__ Q, int ldq, long sQb,
    const short* __restrict__ K, int ldk, long sKb,
    const short* __restrict__ Vt,
    short* __restrict__ O, int ldo, long sOb)
{
    __shared__ short Ks[2][64 * 64];
    __shared__ short Vts[2][64 * 64];
    __shared__ short Ps[8][16 * 72];

    const int z = blockIdx.x;
    const int b = z >> 4, h = z & 15;
    const int qt = blockIdx.y;

    const int tid = threadIdx.x;
    const int w = tid >> 6, l = tid & 63;
    const int lane16 = l & 15, kg = l >> 4;

    const short* Qg = Q + sQb * b + h * 64;
    const short* Kg = K + sKb * b + h * 64;
    const short* Vtg = Vt + (long)z * 65536;
    short* Og = O + sOb * b + h * 64 + (long)(qt * 128 + w * 16) * ldo;

    const int srow = w * 8 + (l >> 3);
    const int schunk = (l & 7) ^ (srow & 7);

    bf16x8 aq[2];
    {
        const short* qp = Qg + (long)(qt * 128 + w * 16 + lane16) * ldq + kg * 8;
        aq[0] = *(const bf16x8*)(qp);
        aq[1] = *(const bf16x8*)(qp + 32);
    }

    f32x4 acc_o[4] = {};
    float m_run[4], l_run[4];
    #pragma unroll
    for (int r = 0; r < 4; ++r) { m_run[r] = -1e30f; l_run[r] = 0.f; }

    short* Pw = (short*)Ps + w * (16 * 72);

    {
        const short* srck = Kg + (long)srow * ldk + schunk * 8;
        __builtin_amdgcn_global_load_lds(AS1(srck), AS3((short*)Ks + w * 512), 16, 0, 0);
        const short* srcv = Vtg + (long)srow * 1024 + schunk * 8;
        __builtin_amdgcn_global_load_lds(AS1(srcv), AS3((short*)Vts + w * 512), 16, 0, 0);
    }

    int cur = 0;
    for (int t = 0; t < 16; ++t) {
        __syncthreads();
        if (t < 15) {
            const short* srck = Kg + (long)((t + 1) * 64 + srow) * ldk + schunk * 8;
            __builtin_amdgcn_global_load_lds(AS1(srck), AS3((short*)Ks + (cur ^ 1) * 4096 + w * 512), 16, 0, 0);
            const short* srcv = Vtg + (long)srow * 1024 + (t + 1) * 64 + schunk * 8;
            __builtin_amdgcn_global_load_lds(AS1(srcv), AS3((short*)Vts + (cur ^ 1) * 4096 + w * 512), 16, 0, 0);
        }
        const short* Kb = (const short*)Ks + cur * 4096;
        const short* Vb = (const short*)Vts + cur * 4096;

        f32x4 acc_s[4] = {};
        #pragma unroll
        for (int n = 0; n < 4; ++n) {
            int row = 16 * n + lane16;
            #pragma unroll
            for (int ks = 0; ks < 2; ++ks) {
                bf16x8 bk = *(const bf16x8*)(Kb + row * 64 + (((ks * 4 + kg) ^ (row & 7)) * 8));
                acc_s[n] = __builtin_amdgcn_mfma_f32_16x16x32_bf16(aq[ks], bk, acc_s[n], 0, 0, 0);
            }
        }

        float mt[4], p[4][4], rs[4], mnew[4], corr[4];
        #pragma unroll
        for (int n = 0; n < 4; ++n)
            #pragma unroll
            for (int r = 0; r < 4; ++r) acc_s[n][r] *= 0.125f;
        #pragma unroll
        for (int r = 0; r < 4; ++r)
            mt[r] = fmaxf(fmaxf(acc_s[0][r], acc_s[1][r]), fmaxf(acc_s[2][r], acc_s[3][r]));
        #pragma unroll
        for (int off = 1; off < 16; off <<= 1)
            #pragma unroll
            for (int r = 0; r < 4; ++r) mt[r] = fmaxf(mt[r], __shfl_xor(mt[r], off));
        #pragma unroll
        for (int r = 0; r < 4; ++r) {
            mnew[r] = fmaxf(m_run[r], mt[r]);
            corr[r] = __expf(m_run[r] - mnew[r]);
            m_run[r] = mnew[r];
            rs[r] = 0.f;
        }
        #pragma unroll
        for (int n = 0; n < 4; ++n)
            #pragma unroll
            for (int r = 0; r < 4; ++r) {
                float e = __expf(acc_s[n][r] - mnew[r]);
                p[n][r] = e; rs[r] += e;
            }
        #pragma unroll
        for (int off = 1; off < 16; off <<= 1)
            #pragma unroll
            for (int r = 0; r < 4; ++r) rs[r] += __shfl_xor(rs[r], off);
        #pragma unroll
        for (int r = 0; r < 4; ++r) {
            l_run[r] = l_run[r] * corr[r] + rs[r];
            #pragma unroll
            for (int nd = 0; nd < 4; ++nd) acc_o[nd][r] *= corr[r];
        }

        #pragma unroll
        for (int n = 0; n < 4; ++n)
            #pragma unroll
            for (int r = 0; r < 4; ++r)
                Pw[(kg * 4 + r) * 72 + 16 * n + lane16] = f2bf(p[n][r]);

        #pragma unroll
        for (int kk = 0; kk < 2; ++kk) {
            bf16x8 pa = *(const bf16x8*)(Pw + lane16 * 72 + kk * 32 + kg * 8);
            #pragma unroll
            for (int nd = 0; nd < 4; ++nd) {
                int d = 16 * nd + lane16;
                bf16x8 bv = *(const bf16x8*)(Vb + d * 64 + (((kk * 4 + kg) ^ (d & 7)) * 8));
                acc_o[nd] = __builtin_amdgcn_mfma_f32_16x16x32_bf16(pa, bv, acc_o[nd], 0, 0, 0);
            }
        }
        cur ^= 1;
    }

    #pragma unroll
    for (int r = 0; r < 4; ++r) {
        float inv = 1.0f / l_run[r];
        #pragma unroll
        for (int nd = 0; nd < 4; ++nd)
            Og[(long)(kg * 4 + r) * ldo + nd * 16 + lane16] = f2bf(acc_o[nd][r] * inv);
    }
}

// ---------------- LayerNorm fp32 -> bf16 ----------------
__global__ __launch_bounds__(256) void ln_bf16(const float* __restrict__ x,
                                               const float* __restrict__ g,
                                               const float* __restrict__ b,
                                               short* __restrict__ h)
{
    const long row = blockIdx.x;
    const int tid = threadIdx.x;
    float4 v = ((const float4*)(x + row * 1024))[tid];
    float s  = v.x + v.y + v.z + v.w;
    float s2 = v.x * v.x + v.y * v.y + v.z * v.z + v.w * v.w;
    #pragma unroll
    for (int off = 1; off < 64; off <<= 1) {
        s  += __shfl_xor(s, off);
        s2 += __shfl_xor(s2, off);
    }
    __shared__ float rs[4], rs2[4];
    int w = tid >> 6;
    if ((tid & 63) == 0) { rs[w] = s; rs2[w] = s2; }
    __syncthreads();
    s  = rs[0] + rs[1] + rs[2] + rs[3];
    s2 = rs2[0] + rs2[1] + rs2[2] + rs2[3];
    float mu  = s * (1.0f / 1024.0f);
    float var = s2 * (1.0f / 1024.0f) - mu * mu;
    float inv = rsqrtf(var + 1e-5f);
    float4 gv = ((const float4*)g)[tid];
    float4 bv = ((const float4*)b)[tid];
    short4v o;
    o[0] = f2bf((v.x - mu) * inv * gv.x + bv.x);
    o[1] = f2bf((v.y - mu) * inv * gv.y + bv.y);
    o[2] = f2bf((v.z - mu) * inv * gv.z + bv.z);
    o[3] = f2bf((v.w - mu) * inv * gv.w + bv.w);
    ((short4v*)(h + row * 1024))[tid] = o;
}

// ---------------- transpose fp32 [R][C] -> bf16 [C][R] ----------------
__global__ __launch_bounds__(256) void wconv_t(const float* __restrict__ in,
                                               short* __restrict__ out, int R, int C)
{
    __shared__ float t[32][33];
    const int c0 = blockIdx.x * 32, r0 = blockIdx.y * 32;
    const int tx = threadIdx.x & 31, ty = threadIdx.x >> 5;
    #pragma unroll
    for (int i = 0; i < 4; ++i)
        t[ty + i * 8][tx] = in[(long)(r0 + ty + i * 8) * C + c0 + tx];
    __syncthreads();
    #pragma unroll
    for (int i = 0; i < 4; ++i)
        out[(long)(c0 + ty + i * 8) * R + r0 + tx] = f2bf(t[tx][ty + i * 8]);
}

// ---------------- per-head V transpose: bf16 [m][d] -> vt[z][d][m] ----------------
__global__ __launch_bounds__(256) void vtrans(const short* __restrict__ src, int ld, int col_off,
                                              short* __restrict__ vt)
{
    __shared__ short t[32][33];
    const int z = blockIdx.z, bb = z >> 4, hh = z & 15;
    const int m0 = blockIdx.x * 32, d0 = blockIdx.y * 32;
    const int tx = threadIdx.x & 31, ty = threadIdx.x >> 5;
    const short* sp = src + (long)(bb * 1024) * ld + col_off + hh * 64;
    #pragma unroll
    for (int i = 0; i < 4; ++i)
        t[ty + i * 8][tx] = sp[(long)(m0 + ty + i * 8) * ld + d0 + tx];
    __syncthreads();
    short* op = vt + (long)z * 64 * 1024;
    #pragma unroll
    for (int i = 0; i < 4; ++i)
        op[(long)(d0 + ty + i * 8) * 1024 + m0 + tx] = t[tx][ty + i * 8];
}

// ---------------- elementwise fp32 -> bf16 ----------------
__global__ __launch_bounds__(256) void f2bf_vec(const float* __restrict__ in,
                                                short* __restrict__ out, int n4)
{
    int i = blockIdx.x * 256 + threadIdx.x;
    if (i < n4) {
        float4 v = ((const float4*)in)[i];
        short4v o;
        o[0] = f2bf(v.x); o[1] = f2bf(v.y); o[2] = f2bf(v.z); o[3] = f2bf(v.w);
        ((short4v*)out)[i] = o;
    }
}

// ---------------- host side ----------------
template<int MODE, int BM>
static void launch_gemm2(const short* A, int lda, const short* B, int ldb,
                         void* C, int ldc, const float* bias, const float* resid,
                         int M, int N, int K, hipStream_t stream)
{
    int ntm = M / BM, ntn = N / 128;
    gemm2<MODE, BM><<<dim3(ntm * ntn), 256, 0, stream>>>(A, lda, B, ldb, C, ldc,
                                                         bias, resid, ntn, K / 64, 1.0f);
}

extern "C" void kernel_launch(void* const* d_in, const int* in_sizes, int n_in,
                              void* d_out, int out_size, void* d_ws, size_t ws_size,
                              hipStream_t stream)
{
    const float* x_in  = (const float*)d_in[0];
    const float* ctx   = (const float*)d_in[1];
    const float* ln1_g = (const float*)d_in[2];
    const float* ln1_b = (const float*)d_in[3];
    const float* w_qkv = (const float*)d_in[4];
    const float* w_o1  = (const float*)d_in[5];
    const float* b_o1  = (const float*)d_in[6];
    const float* ln2_g = (const float*)d_in[7];
    const float* ln2_b = (const float*)d_in[8];
    const float* w_q   = (const float*)d_in[9];
    const float* w_k   = (const float*)d_in[10];
    const float* w_v   = (const float*)d_in[11];
    const float* w_o2  = (const float*)d_in[12];
    const float* b_o2  = (const float*)d_in[13];
    const float* ln3_g = (const float*)d_in[14];
    const float* ln3_b = (const float*)d_in[15];
    const float* w_ff1 = (const float*)d_in[16];
    const float* b_ff1 = (const float*)d_in[17];
    const float* w_ff2 = (const float*)d_in[18];
    const float* b_ff2 = (const float*)d_in[19];
    float* xo = (float*)d_out;

    char* p = (char*)d_ws;
    short* wbuf   = (short*)(p);              // 8 MB (max 4096x1024 bf16; also packed k|v weights)
    short* hbuf   = (short*)(p + 8388608);    // 4 MB
    short* qkvbuf = (short*)(p + 12582912);   // 12.58 MB
    short* k2v2   = (short*)(p + 25165824);   // 8 MB  [2048][2048]
    short* vt     = (short*)(p + 92274688);   // 4 MB
    short* aout   = (short*)(p + 96468992);   // 4 MB
    short* ffbuf  = (short*)(p + 100663296);  // 16 MB
    short* ctxbuf = (short*)(p + 117440512);  // 4 MB

    hipMemcpyAsync(xo, x_in, (size_t)2 * 1024 * 1024 * 4, hipMemcpyDeviceToDevice, stream);
    f2bf_vec<<<2048, 256, 0, stream>>>(ctx, ctxbuf, 2 * 1024 * 1024 / 4);

    for (int l = 0; l < 2; ++l) {
        // ======== self attention ========
        ln_bf16<<<2048, 256, 0, stream>>>(xo, ln1_g + l * 1024, ln1_b + l * 1024, hbuf);
        wconv_t<<<dim3(96, 32), 256, 0, stream>>>(w_qkv + (long)l * 1024 * 3072, wbuf, 1024, 3072);
        launch_gemm2<0, 128>(hbuf, 1024, wbuf, 1024, qkvbuf, 3072,
                             nullptr, nullptr, 2048, 3072, 1024, stream);
        vtrans<<<dim3(32, 2, 32), 256, 0, stream>>>(qkvbuf, 3072, 2048, vt);
        flash_attn<<<dim3(32, 8), 512, 0, stream>>>(qkvbuf, 3072, 3145728L,
                                                    qkvbuf + 1024, 3072, 3145728L,
                                                    vt, aout, 1024, 1048576L);
        wconv_t<<<dim3(32, 32), 256, 0, stream>>>(w_o1 + (long)l * 1048576, wbuf, 1024, 1024);
        launch_gemm2<2, 64>(aout, 1024, wbuf, 1024, xo, 1024,
                            b_o1 + l * 1024, xo, 2048, 1024, 1024, stream);

        // ======== cross attention ========
        ln_bf16<<<2048, 256, 0, stream>>>(xo, ln2_g + l * 1024, ln2_b + l * 1024, hbuf);
        short* q2 = qkvbuf;
        wconv_t<<<dim3(32, 32), 256, 0, stream>>>(w_q + (long)l * 1048576, wbuf, 1024, 1024);
        launch_gemm2<0, 64>(hbuf, 1024, wbuf, 1024, q2, 1024,
                            nullptr, nullptr, 2048, 1024, 1024, stream);
        // packed K|V weights -> one N=2048 GEMM from ctx
        wconv_t<<<dim3(32, 32), 256, 0, stream>>>(w_k + (long)l * 1048576, wbuf, 1024, 1024);
        wconv_t<<<dim3(32, 32), 256, 0, stream>>>(w_v + (long)l * 1048576, wbuf + 1048576, 1024, 1024);
        launch_gemm2<0, 64>(ctxbuf, 1024, wbuf, 1024, k2v2, 2048,
                            nullptr, nullptr, 2048, 2048, 1024, stream);
        vtrans<<<dim3(32, 2, 32), 256, 0, stream>>>(k2v2 + 1024, 2048, 0, vt);
        flash_attn<<<dim3(32, 8), 512, 0, stream>>>(q2, 1024, 1048576L,
                                                    k2v2, 2048, 2097152L,
                                                    vt, aout, 1024, 1048576L);
        wconv_t<<<dim3(32, 32), 256, 0, stream>>>(w_o2 + (long)l * 1048576, wbuf, 1024, 1024);
        launch_gemm2<2, 64>(aout, 1024, wbuf, 1024, xo, 1024,
                            b_o2 + l * 1024, xo, 2048, 1024, 1024, stream);

        // ======== FFN ========
        ln_bf16<<<2048, 256, 0, stream>>>(xo, ln3_g + l * 1024, ln3_b + l * 1024, hbuf);
        wconv_t<<<dim3(128, 32), 256, 0, stream>>>(w_ff1 + (long)l * 1024 * 4096, wbuf, 1024, 4096);
        launch_gemm2<1, 128>(hbuf, 1024, wbuf, 1024, ffbuf, 4096,
                             b_ff1 + l * 4096, nullptr, 2048, 4096, 1024, stream);
        wconv_t<<<dim3(32, 128), 256, 0, stream>>>(w_ff2 + (long)l * 4096 * 1024, wbuf, 4096, 1024);
        launch_gemm2<2, 64>(ffbuf, 4096, wbuf, 4096, xo, 1024,
                            b_ff2 + l * 1024, xo, 2048, 1024, 4096, stream);
    }
}